// Round 14
// baseline (1407.026 us; speedup 1.0000x reference)
//
#include <hip/hip_runtime.h>

// ---------------------------------------------------------------------------
// SAGENET: x:(8192,16384)f32 -> lin1(16384->4096,relu) -> lin2(4096->2048,relu)
// -> SAGEConv(2048->1024,relu) -> SAGEConv(1024->10,relu) -> softmax
// R14: R13's 8-phase GEMM (62% MfmaUtil, matches m201 structural ceiling) +
//      (1) bn-partitioned XCD mapping: XCD owns bn panels, sweeps bm inner ->
//          B panels XCD-private (gemm2/3: 2 MiB -> L2-resident), A a single
//          shared L3 window; working set < 256 MiB L3 (was 384).
//      (2) all 5 f32->bf16 conversions fused into one launch.
//      (3) sage2_final: 4 nodes per 256-thread block.
//      Per-tile arithmetic unchanged everywhere -> absmax canary 0.002929688.
// Workspace peak: ~505.2 MiB.
// ---------------------------------------------------------------------------

typedef short  short8   __attribute__((ext_vector_type(8)));
typedef float  floatx4  __attribute__((ext_vector_type(4)));
typedef unsigned short ushort8v __attribute__((ext_vector_type(8)));
typedef unsigned short ushort4v __attribute__((ext_vector_type(4)));
typedef unsigned short ushort;

__device__ __forceinline__ ushort f2bf(float f) {
  unsigned u = __float_as_uint(f);
  u += 0x7fffu + ((u >> 16) & 1u);   // round-to-nearest-even
  return (ushort)(u >> 16);
}
__device__ __forceinline__ float bf2f(ushort h) {
  return __uint_as_float(((unsigned)h) << 16);
}

__device__ __forceinline__ void gload16(const void* g, void* l) {
  __builtin_amdgcn_global_load_lds(
      (const __attribute__((address_space(1))) void*)g,
      (__attribute__((address_space(3))) void*)l, 16, 0, 0);
}

// ---------------- fused f32 -> bf16 conversion (5 segments, 1 launch) -------
__device__ __forceinline__ void cvt_seg(const float* __restrict__ in,
                                        ushort* __restrict__ out, long n8,
                                        long tid, long stride) {
  for (long i = tid; i < n8; i += stride) {
    const float4* p = (const float4*)(in + i * 8);
    float4 a = p[0], b = p[1];
    ushort8v o;
    o[0] = f2bf(a.x); o[1] = f2bf(a.y); o[2] = f2bf(a.z); o[3] = f2bf(a.w);
    o[4] = f2bf(b.x); o[5] = f2bf(b.y); o[6] = f2bf(b.z); o[7] = f2bf(b.w);
    *(ushort8v*)(out + i * 8) = o;
  }
}

__global__ __launch_bounds__(256) void cvt_multi(
    const float* s0, ushort* d0, long n0,
    const float* s1, ushort* d1, long n1,
    const float* s2, ushort* d2, long n2,
    const float* s3, ushort* d3, long n3,
    const float* s4, ushort* d4, long n4) {
  const long tid = (long)blockIdx.x * blockDim.x + threadIdx.x;
  const long stride = (long)gridDim.x * blockDim.x;
  cvt_seg(s0, d0, n0, tid, stride);
  cvt_seg(s1, d1, n1, tid, stride);
  cvt_seg(s2, d2, n2, tid, stride);
  cvt_seg(s3, d3, n3, tid, stride);
  cvt_seg(s4, d4, n4, tid, stride);
}

// ---------------- CSR build -------------------------------------------------
__global__ void edge_count(const int* __restrict__ dst, int E, int* __restrict__ deg) {
  int e = blockIdx.x * 256 + threadIdx.x;
  if (e < E) atomicAdd(&deg[dst[e]], 1);
}

__global__ __launch_bounds__(256) void scan_k(
    const int* __restrict__ deg, int* __restrict__ offs, float* __restrict__ inv, int n) {
  __shared__ int part[256];
  const int t = threadIdx.x;
  int local[32];
  int s = 0;
  const int base = t * 32;
#pragma unroll
  for (int i = 0; i < 32; ++i) { local[i] = s; s += deg[base + i]; }
  part[t] = s;
  __syncthreads();
  for (int off = 1; off < 256; off <<= 1) {
    int v = (t >= off) ? part[t - off] : 0;
    __syncthreads();
    part[t] += v;
    __syncthreads();
  }
  const int prev = (t == 0) ? 0 : part[t - 1];
  if (t == 255) offs[n] = part[255];
#pragma unroll
  for (int i = 0; i < 32; ++i) {
    const int e = base + i;
    offs[e] = prev + local[i];
    const int d = deg[e];
    inv[e] = (d > 0) ? (1.0f / (float)d) : 0.0f;
  }
}

__global__ void edge_fill(const int* __restrict__ src, const int* __restrict__ dst, int E,
                          const int* __restrict__ offs, int* __restrict__ fill,
                          int* __restrict__ csr) {
  int e = blockIdx.x * 256 + threadIdx.x;
  if (e < E) {
    const int d = dst[e];
    const int p = offs[d] + atomicAdd(&fill[d], 1);
    csr[p] = src[e];
  }
}

// ---------------- bf16 GEMM 256x256, C = A * B^T, 8-phase (m201-style) ------
// R14 mapping: XCD x owns bn panels [x*nbn/8,(x+1)*nbn/8), bm-inner sweep.
template <int OUT_BF16, int RELU, int HAS_BIAS>
__global__ __launch_bounds__(512, 2) void gemm256(
    const ushort* __restrict__ A, const ushort* __restrict__ Bm,
    const float* __restrict__ bias, void* __restrict__ Cout,
    int M, int N, int K) {
  extern __shared__ char smem[];   // buf d at d*65536: A 32 KiB | B 32 KiB

  const int nbn = N >> 8;
  const int nbn8 = nbn >> 3;             // bn panels per XCD (>=1 for N>=2048)
  const int x = blockIdx.x & 7;          // XCD id under round-robin dispatch
  const int j = blockIdx.x >> 3;
  const int bn = x * nbn8 + j % nbn8;
  const int bm = j / nbn8;

  const int t = threadIdx.x;
  const int w = t >> 6, lane = t & 63;
  const int wr = w >> 2, wc = w & 3;

  // ---- staging addresses (source pre-swizzled; identical to R12/R13) ----
  const int cswz = (t & 7) ^ ((t >> 3) & 7);
  const ushort* Ag = A  + (size_t)(bm * 256 + (t >> 3)) * K + cswz * 8;
  const ushort* Bg = Bm + (size_t)(bn * 256 + (t >> 3)) * K + cswz * 8;
  const int stOff = w * 1024;

  // ---- fragment read addresses (identical to R12/R13) ----
  const int rA = wr * 128 + (lane & 15);
  const int rB = wc * 64 + (lane & 15);
  const int s0 = (((lane >> 4) ^ (lane & 7)) << 4);

  floatx4 acc[8][4] = {};
  const int NT = K >> 6;        // K-tiles (even for all our K)
  const int NIT = NT >> 1;      // iterations (2 tiles each)

#define STGA(BUF, KT, H)                                                      \
  {                                                                           \
    const int k0_ = (((KT) < NT) ? (KT) : 0) << 6;                            \
    char* la_ = smem + (BUF) * 65536 + stOff;                                 \
    gload16(Ag + (size_t)(((H) * 2) * 64) * K + k0_, la_ + ((H) * 2) * 8192); \
    gload16(Ag + (size_t)(((H) * 2 + 1) * 64) * K + k0_,                      \
            la_ + ((H) * 2 + 1) * 8192);                                      \
  }
#define STGB(BUF, KT, H)                                                      \
  {                                                                           \
    const int k0_ = (((KT) < NT) ? (KT) : 0) << 6;                            \
    char* lb_ = smem + (BUF) * 65536 + 32768 + stOff;                         \
    gload16(Bg + (size_t)(((H) * 2) * 64) * K + k0_, lb_ + ((H) * 2) * 8192); \
    gload16(Bg + (size_t)(((H) * 2 + 1) * 64) * K + k0_,                      \
            lb_ + ((H) * 2 + 1) * 8192);                                      \
  }

#define PH(BUF, Q, READB, DOWAIT, ...)                                        \
  {                                                                           \
    const char* pa_ = smem + (BUF) * 65536 + rA * 128;                        \
    short8 a00 = *(const short8*)(pa_ + (2 * (Q)) * 2048 + s0);               \
    short8 a01 = *(const short8*)(pa_ + (2 * (Q)) * 2048 + (s0 ^ 64));        \
    short8 a10 = *(const short8*)(pa_ + (2 * (Q) + 1) * 2048 + s0);           \
    short8 a11 = *(const short8*)(pa_ + (2 * (Q) + 1) * 2048 + (s0 ^ 64));    \
    if (READB) {                                                              \
      const char* pb_ = smem + (BUF) * 65536 + 32768 + rB * 128;              \
      _Pragma("unroll") for (int ni = 0; ni < 4; ++ni) {                      \
        bfv0[ni] = *(const short8*)(pb_ + ni * 2048 + s0);                    \
        bfv1[ni] = *(const short8*)(pb_ + ni * 2048 + (s0 ^ 64));             \
      }                                                                       \
    }                                                                         \
    __VA_ARGS__;                                                              \
    if (DOWAIT) asm volatile("s_waitcnt vmcnt(4)" ::: "memory");              \
    __builtin_amdgcn_s_barrier();                                             \
    __builtin_amdgcn_s_setprio(1);                                            \
    _Pragma("unroll") for (int ni = 0; ni < 4; ++ni) {                        \
      acc[2 * (Q)][ni] = __builtin_amdgcn_mfma_f32_16x16x32_bf16(             \
          a00, bfv0[ni], acc[2 * (Q)][ni], 0, 0, 0);                          \
      acc[2 * (Q) + 1][ni] = __builtin_amdgcn_mfma_f32_16x16x32_bf16(         \
          a10, bfv0[ni], acc[2 * (Q) + 1][ni], 0, 0, 0);                      \
    }                                                                         \
    _Pragma("unroll") for (int ni = 0; ni < 4; ++ni) {                        \
      acc[2 * (Q)][ni] = __builtin_amdgcn_mfma_f32_16x16x32_bf16(             \
          a01, bfv1[ni], acc[2 * (Q)][ni], 0, 0, 0);                          \
      acc[2 * (Q) + 1][ni] = __builtin_amdgcn_mfma_f32_16x16x32_bf16(         \
          a11, bfv1[ni], acc[2 * (Q) + 1][ni], 0, 0, 0);                      \
    }                                                                         \
    __builtin_amdgcn_s_setprio(0);                                            \
    asm volatile("" ::: "memory");                                            \
  }

  // prologue: A(t0), B(t0), B(t1) = 12 loads; land tile0's 8, leave B(t1)=4
  STGA(0, 0, 0); STGA(0, 0, 1);
  STGB(0, 0, 0); STGB(0, 0, 1);
  STGB(1, 1, 0); STGB(1, 1, 1);
  asm volatile("s_waitcnt vmcnt(4)" ::: "memory");
  __builtin_amdgcn_s_barrier();
  asm volatile("" ::: "memory");

  for (int it = 0; it < NIT; ++it) {
    const int t1 = 2 * it + 1, t2 = 2 * it + 2, t3 = 2 * it + 3;
    short8 bfv0[4], bfv1[4];
    PH(0, 0, 1, 0, STGA(1, t1, 0); STGA(1, t1, 1));   // ph1
    PH(0, 1, 0, 0, STGB(0, t2, 0));                   // ph2
    PH(0, 2, 0, 0, STGB(0, t2, 1));                   // ph3
    PH(0, 3, 0, 1, );                                 // ph4: vmcnt(4)
    PH(1, 0, 1, 0, STGA(0, t2, 0));                   // ph5
    PH(1, 1, 0, 0, STGA(0, t2, 1));                   // ph6
    PH(1, 2, 0, 0, STGB(1, t3, 0));                   // ph7
    PH(1, 3, 0, 1, STGB(1, t3, 1));                   // ph8: vmcnt(4)
  }
  asm volatile("s_waitcnt vmcnt(0)" ::: "memory");    // drain tail stages

#undef STGA
#undef STGB
#undef PH

  // epilogue: C/D layout col=lane&15, row=(lane>>4)*4+j (m89-verified)
  const int row0 = bm * 256 + wr * 128 + ((lane >> 4) << 2);
  const int col0 = bn * 256 + wc * 64 + (lane & 15);
#pragma unroll
  for (int ni = 0; ni < 4; ++ni) {
    const int col = col0 + ni * 16;
    const float bv = HAS_BIAS ? bias[col] : 0.0f;
#pragma unroll
    for (int mi = 0; mi < 8; ++mi) {
#pragma unroll
      for (int j2 = 0; j2 < 4; ++j2) {
        const int row = row0 + mi * 16 + j2;
        float v = acc[mi][ni][j2] + bv;
        if (RELU) v = fmaxf(v, 0.0f);
        if (OUT_BF16)
          ((ushort*)Cout)[(size_t)row * N + col] = f2bf(v);
        else
          ((float*)Cout)[(size_t)row * N + col] = v;
      }
    }
  }
}

// ---------------- SAGE1 aggregation + combine (bf16 hlr1) -------------------
__global__ __launch_bounds__(256) void sage1_agg(
    const ushort* __restrict__ hlr1, const int* __restrict__ offs,
    const int* __restrict__ csr, const float* __restrict__ inv,
    const float* __restrict__ lb, ushort* __restrict__ h3) {
  const int dn = blockIdx.x;
  const int f4 = threadIdx.x * 4;
  float ax = 0.f, ay = 0.f, az = 0.f, aw = 0.f;
  const int e0 = offs[dn], e1 = offs[dn + 1];
  for (int e = e0; e < e1; ++e) {
    const int s = csr[e];
    const ushort4v v = *(const ushort4v*)(hlr1 + (size_t)s * 2048 + f4);
    ax += bf2f(v[0]); ay += bf2f(v[1]); az += bf2f(v[2]); aw += bf2f(v[3]);
  }
  const float iv = inv[dn];
  const ushort4v hr = *(const ushort4v*)(hlr1 + (size_t)dn * 2048 + 1024 + f4);
  const float4 bb = *(const float4*)(lb + f4);
  ushort4v o;
  o[0] = f2bf(fmaxf(ax * iv + bb.x + bf2f(hr[0]), 0.0f));
  o[1] = f2bf(fmaxf(ay * iv + bb.y + bf2f(hr[1]), 0.0f));
  o[2] = f2bf(fmaxf(az * iv + bb.z + bf2f(hr[2]), 0.0f));
  o[3] = f2bf(fmaxf(aw * iv + bb.w + bf2f(hr[3]), 0.0f));
  *(ushort4v*)(h3 + (size_t)dn * 1024 + f4) = o;
}

// ---------------- SAGE2 projections v2 (weights in LDS, 16 rows/block) ------
__global__ __launch_bounds__(256) void sage2_mm(
    const ushort* __restrict__ h3, const float* __restrict__ wl,
    const float* __restrict__ wr, float* __restrict__ hl2, float* __restrict__ hr2) {
  __shared__ float wds[20480];   // [0..10239]=wl, [10240..20479]=wr
  const int t = threadIdx.x;
  for (int i = t; i < 2560; i += 256)
    *(float4*)&wds[i * 4] = *(const float4*)&wl[i * 4];
  for (int i = t; i < 2560; i += 256)
    *(float4*)&wds[10240 + i * 4] = *(const float4*)&wr[i * 4];
  __syncthreads();

  const int r = t >> 4, c = t & 15;
  const int row = blockIdx.x * 16 + r;

  float hv[64];
#pragma unroll
  for (int ii = 0; ii < 8; ++ii) {
    ushort8v p = *(const ushort8v*)(h3 + (size_t)row * 1024 + c * 64 + ii * 8);
#pragma unroll
    for (int k = 0; k < 8; ++k) hv[ii * 8 + k] = bf2f(p[k]);
  }

  float al[10] = {}, ar[10] = {};
#pragma unroll
  for (int j = 0; j < 10; ++j) {
    const int base = j * 1024 + c * 64;
#pragma unroll
    for (int ii = 0; ii < 16; ++ii) {
      const int f = (ii + c) & 15;    // staggered float4 index
      const float4 lv = *(const float4*)&wds[base + f * 4];
      const float4 rv = *(const float4*)&wds[10240 + base + f * 4];
      const float h0 = hv[f * 4], h1 = hv[f * 4 + 1],
                  h2 = hv[f * 4 + 2], h3v = hv[f * 4 + 3];
      al[j] = fmaf(h0, lv.x, fmaf(h1, lv.y, fmaf(h2, lv.z, fmaf(h3v, lv.w, al[j]))));
      ar[j] = fmaf(h0, rv.x, fmaf(h1, rv.y, fmaf(h2, rv.z, fmaf(h3v, rv.w, ar[j]))));
    }
  }
#pragma unroll
  for (int j = 0; j < 10; ++j) {
#pragma unroll
    for (int off = 8; off > 0; off >>= 1) {
      al[j] += __shfl_down(al[j], off);
      ar[j] += __shfl_down(ar[j], off);
    }
  }
  if (c == 0) {
#pragma unroll
    for (int j = 0; j < 10; ++j) {
      hl2[(size_t)row * 10 + j] = al[j];
      hr2[(size_t)row * 10 + j] = ar[j];
    }
  }
}

// ---------------- SAGE2 aggregation + combine + softmax (4 nodes/block) -----
__global__ __launch_bounds__(256) void sage2_final(
    const float* __restrict__ hl2, const float* __restrict__ hr2,
    const int* __restrict__ offs, const int* __restrict__ csr,
    const float* __restrict__ inv, const float* __restrict__ lb,
    float* __restrict__ out) {
  const int dn = blockIdx.x * 4 + (threadIdx.x >> 6);
  const int l = threadIdx.x & 63;
  float a[10] = {};
  const int e0 = offs[dn], e1 = offs[dn + 1];
  for (int e = e0 + l; e < e1; e += 64) {
    const int s = csr[e];
#pragma unroll
    for (int j = 0; j < 10; ++j) a[j] += hl2[(size_t)s * 10 + j];
  }
#pragma unroll
  for (int j = 0; j < 10; ++j)
#pragma unroll
    for (int off = 32; off > 0; off >>= 1) a[j] += __shfl_down(a[j], off);
  if (l == 0) {
    const float iv = inv[dn];
    float v[10];
    float m = -1e30f;
#pragma unroll
    for (int j = 0; j < 10; ++j) {
      v[j] = fmaxf(a[j] * iv + lb[j] + hr2[(size_t)dn * 10 + j], 0.0f);
      m = fmaxf(m, v[j]);
    }
    float ssum = 0.0f;
#pragma unroll
    for (int j = 0; j < 10; ++j) { v[j] = __expf(v[j] - m); ssum += v[j]; }
    const float r = 1.0f / ssum;
#pragma unroll
    for (int j = 0; j < 10; ++j) out[(size_t)dn * 10 + j] = v[j] * r;
  }
}

// ---------------------------------------------------------------------------
extern "C" void kernel_launch(void* const* d_in, const int* in_sizes, int n_in,
                              void* d_out, int out_size, void* d_ws, size_t ws_size,
                              hipStream_t stream) {
  const float* x    = (const float*)d_in[0];
  const int*   ei   = (const int*)d_in[1];
  const float* w1   = (const float*)d_in[2];
  const float* b1   = (const float*)d_in[3];
  const float* w2   = (const float*)d_in[4];
  const float* b2   = (const float*)d_in[5];
  const float* s1lw = (const float*)d_in[6];
  const float* s1lb = (const float*)d_in[7];
  const float* s1rw = (const float*)d_in[8];
  const float* s2lw = (const float*)d_in[9];
  const float* s2lb = (const float*)d_in[10];
  const float* s2rw = (const float*)d_in[11];
  float* out = (float*)d_out;
  char* ws = (char*)d_ws;

  const int E = in_sizes[1] / 2;  // 262144
  const int Nn = 8192;

  // allow 128 KiB dynamic LDS for the GEMM instantiations (idempotent)
  hipFuncSetAttribute((const void*)&gemm256<1, 1, 1>,
                      hipFuncAttributeMaxDynamicSharedMemorySize, 131072);
  hipFuncSetAttribute((const void*)&gemm256<1, 0, 0>,
                      hipFuncAttributeMaxDynamicSharedMemorySize, 131072);

  // ---- workspace layout (bytes) ----
  ushort* xb  = (ushort*)(ws + 0L);           // 256 MiB
  ushort* w1b = (ushort*)(ws + 268435456L);   // 128 MiB
  ushort* h1  = (ushort*)(ws + 402653184L);   //  64 MiB
  ushort* w2b = (ushort*)(ws + 469762048L);   //  16 MiB
  ushort* h2  = (ushort*)(ws + 486539264L);   //  32 MiB
  ushort* ws1 = (ushort*)(ws + 520093696L);   //   8 MiB  [s1_l_w ; s1_r_w]
  char* csrb = ws + 528482304L;
  int*   deg  = (int*)(csrb);
  int*   fill = (int*)(csrb + 32768);
  int*   offs = (int*)(csrb + 65536);
  float* inv  = (float*)(csrb + 98816);
  int*   csr  = (int*)(csrb + 131584);
  // region reuse (xb dead after GEMM1, h1 dead after GEMM2):
  ushort* hlr1 = (ushort*)(ws + 0L);                // 32 MiB bf16 [hl1 | hr1]
  ushort* h3   = (ushort*)(ws + 67108864L);         // 16 MiB
  float*  hl2  = (float*)(ws + 83886080L);
  float*  hr2  = (float*)(ws + 84213760L);

  const int* esrc = ei;
  const int* edst = ei + E;

  hipMemsetAsync(deg, 0, 65536, stream);  // deg + fill counters

  // all f32->bf16 conversions in one launch
  cvt_multi<<<4096, 256, 0, stream>>>(
      x, xb, 16777216L,
      w1, w1b, 8388608L,
      w2, w2b, 1048576L,
      s1lw, ws1, 262144L,
      s1rw, ws1 + 2097152L, 262144L);

  // CSR build
  edge_count<<<(E + 255) / 256, 256, 0, stream>>>(edst, E, deg);
  scan_k<<<1, 256, 0, stream>>>(deg, offs, inv, Nn);
  edge_fill<<<(E + 255) / 256, 256, 0, stream>>>(esrc, edst, E, offs, fill, csr);

  // MLP (256x256-tile GEMMs, 128 KiB dynamic LDS, 8-phase pipeline)
  gemm256<1, 1, 1><<<512, 512, 131072, stream>>>(xb, w1b, b1, h1, 8192, 4096, 16384);
  gemm256<1, 1, 1><<<256, 512, 131072, stream>>>(h1, w2b, b2, h2, 8192, 2048, 4096);
  // fused SAGE1 projections: [hl1 | hr1] = h2 @ [s1_l_w ; s1_r_w]^T  (bf16 out)
  gemm256<1, 0, 0><<<256, 512, 131072, stream>>>(h2, ws1, nullptr, hlr1, 8192, 2048, 2048);

  sage1_agg<<<8192, 256, 0, stream>>>(hlr1, offs, csr, inv, s1lb, h3);
  sage2_mm<<<512, 256, 0, stream>>>(h3, s2lw, s2rw, hl2, hr2);
  sage2_final<<<2048, 256, 0, stream>>>(hl2, hr2, offs, csr, inv, s2lb, out);
}

// Round 15
// 1361.359 us; speedup vs baseline: 1.0335x; 1.0335x over previous
//
#include <hip/hip_runtime.h>

// ---------------------------------------------------------------------------
// SAGENET: x:(8192,16384)f32 -> lin1(16384->4096,relu) -> lin2(4096->2048,relu)
// -> SAGEConv(2048->1024,relu) -> SAGEConv(1024->10,relu) -> softmax
// R15: exact R13 restoration (best measured config: 1365 µs total, gemm1
//      833 µs @ 62.2% MfmaUtil = m201 structural ceiling):
//      - 8-phase counted-vmcnt GEMM, 256x256, BK=64, dbuf 128 KiB
//      - bm-partitioned XCD mapping (R14's bn-partition REGRESSED: A-phase
//        drift across XCDs, FETCH 1.4->2.0 GB)
//      - separate cvt launches (R14's fusion regressed ~20 µs)
//      Only R14 survivor: sage2_final 4 nodes/block (verified neutral).
//      Per-tile arithmetic unchanged -> absmax canary 0.002929688.
// Workspace peak: ~505.2 MiB.
// ---------------------------------------------------------------------------

typedef short  short8   __attribute__((ext_vector_type(8)));
typedef float  floatx4  __attribute__((ext_vector_type(4)));
typedef unsigned short ushort8v __attribute__((ext_vector_type(8)));
typedef unsigned short ushort4v __attribute__((ext_vector_type(4)));
typedef unsigned short ushort;

__device__ __forceinline__ ushort f2bf(float f) {
  unsigned u = __float_as_uint(f);
  u += 0x7fffu + ((u >> 16) & 1u);   // round-to-nearest-even
  return (ushort)(u >> 16);
}
__device__ __forceinline__ float bf2f(ushort h) {
  return __uint_as_float(((unsigned)h) << 16);
}

__device__ __forceinline__ void gload16(const void* g, void* l) {
  __builtin_amdgcn_global_load_lds(
      (const __attribute__((address_space(1))) void*)g,
      (__attribute__((address_space(3))) void*)l, 16, 0, 0);
}

// ---------------- f32 -> bf16 conversion (vectorized, grid-stride) ----------
__global__ __launch_bounds__(256) void cvt_f32_bf16(
    const float* __restrict__ in, ushort* __restrict__ out, long n8) {
  long i = (long)blockIdx.x * blockDim.x + threadIdx.x;
  const long stride = (long)gridDim.x * blockDim.x;
  for (; i < n8; i += stride) {
    const float4* p = (const float4*)(in + i * 8);
    float4 a = p[0], b = p[1];
    ushort8v o;
    o[0] = f2bf(a.x); o[1] = f2bf(a.y); o[2] = f2bf(a.z); o[3] = f2bf(a.w);
    o[4] = f2bf(b.x); o[5] = f2bf(b.y); o[6] = f2bf(b.z); o[7] = f2bf(b.w);
    *(ushort8v*)(out + i * 8) = o;
  }
}

// ---------------- CSR build -------------------------------------------------
__global__ void edge_count(const int* __restrict__ dst, int E, int* __restrict__ deg) {
  int e = blockIdx.x * 256 + threadIdx.x;
  if (e < E) atomicAdd(&deg[dst[e]], 1);
}

__global__ __launch_bounds__(256) void scan_k(
    const int* __restrict__ deg, int* __restrict__ offs, float* __restrict__ inv, int n) {
  __shared__ int part[256];
  const int t = threadIdx.x;
  int local[32];
  int s = 0;
  const int base = t * 32;
#pragma unroll
  for (int i = 0; i < 32; ++i) { local[i] = s; s += deg[base + i]; }
  part[t] = s;
  __syncthreads();
  for (int off = 1; off < 256; off <<= 1) {
    int v = (t >= off) ? part[t - off] : 0;
    __syncthreads();
    part[t] += v;
    __syncthreads();
  }
  const int prev = (t == 0) ? 0 : part[t - 1];
  if (t == 255) offs[n] = part[255];
#pragma unroll
  for (int i = 0; i < 32; ++i) {
    const int e = base + i;
    offs[e] = prev + local[i];
    const int d = deg[e];
    inv[e] = (d > 0) ? (1.0f / (float)d) : 0.0f;
  }
}

__global__ void edge_fill(const int* __restrict__ src, const int* __restrict__ dst, int E,
                          const int* __restrict__ offs, int* __restrict__ fill,
                          int* __restrict__ csr) {
  int e = blockIdx.x * 256 + threadIdx.x;
  if (e < E) {
    const int d = dst[e];
    const int p = offs[d] + atomicAdd(&fill[d], 1);
    csr[p] = src[e];
  }
}

// ---------------- bf16 GEMM 256x256, C = A * B^T, 8-phase (m201-style) ------
// bm-partitioned XCD mapping (R13): XCD x owns bm panels, bn-inner sweep.
template <int OUT_BF16, int RELU, int HAS_BIAS>
__global__ __launch_bounds__(512, 2) void gemm256(
    const ushort* __restrict__ A, const ushort* __restrict__ Bm,
    const float* __restrict__ bias, void* __restrict__ Cout,
    int M, int N, int K) {
  extern __shared__ char smem[];   // buf d at d*65536: A 32 KiB | B 32 KiB

  const int nbn = N >> 8;
  const int nbm8 = (M >> 8) >> 3;        // bm panels per XCD
  const int x = blockIdx.x & 7;          // XCD id under round-robin dispatch
  const int j = blockIdx.x >> 3;
  const int bm = x * nbm8 + j / nbn;
  const int bn = j % nbn;

  const int t = threadIdx.x;
  const int w = t >> 6, lane = t & 63;
  const int wr = w >> 2, wc = w & 3;

  // ---- staging addresses (source pre-swizzled; identical to R12/R13) ----
  const int cswz = (t & 7) ^ ((t >> 3) & 7);
  const ushort* Ag = A  + (size_t)(bm * 256 + (t >> 3)) * K + cswz * 8;
  const ushort* Bg = Bm + (size_t)(bn * 256 + (t >> 3)) * K + cswz * 8;
  const int stOff = w * 1024;

  // ---- fragment read addresses (identical to R12/R13) ----
  const int rA = wr * 128 + (lane & 15);
  const int rB = wc * 64 + (lane & 15);
  const int s0 = (((lane >> 4) ^ (lane & 7)) << 4);

  floatx4 acc[8][4] = {};
  const int NT = K >> 6;        // K-tiles (even for all our K)
  const int NIT = NT >> 1;      // iterations (2 tiles each)

#define STGA(BUF, KT, H)                                                      \
  {                                                                           \
    const int k0_ = (((KT) < NT) ? (KT) : 0) << 6;                            \
    char* la_ = smem + (BUF) * 65536 + stOff;                                 \
    gload16(Ag + (size_t)(((H) * 2) * 64) * K + k0_, la_ + ((H) * 2) * 8192); \
    gload16(Ag + (size_t)(((H) * 2 + 1) * 64) * K + k0_,                      \
            la_ + ((H) * 2 + 1) * 8192);                                      \
  }
#define STGB(BUF, KT, H)                                                      \
  {                                                                           \
    const int k0_ = (((KT) < NT) ? (KT) : 0) << 6;                            \
    char* lb_ = smem + (BUF) * 65536 + 32768 + stOff;                         \
    gload16(Bg + (size_t)(((H) * 2) * 64) * K + k0_, lb_ + ((H) * 2) * 8192); \
    gload16(Bg + (size_t)(((H) * 2 + 1) * 64) * K + k0_,                      \
            lb_ + ((H) * 2 + 1) * 8192);                                      \
  }

#define PH(BUF, Q, READB, DOWAIT, ...)                                        \
  {                                                                           \
    const char* pa_ = smem + (BUF) * 65536 + rA * 128;                        \
    short8 a00 = *(const short8*)(pa_ + (2 * (Q)) * 2048 + s0);               \
    short8 a01 = *(const short8*)(pa_ + (2 * (Q)) * 2048 + (s0 ^ 64));        \
    short8 a10 = *(const short8*)(pa_ + (2 * (Q) + 1) * 2048 + s0);           \
    short8 a11 = *(const short8*)(pa_ + (2 * (Q) + 1) * 2048 + (s0 ^ 64));    \
    if (READB) {                                                              \
      const char* pb_ = smem + (BUF) * 65536 + 32768 + rB * 128;              \
      _Pragma("unroll") for (int ni = 0; ni < 4; ++ni) {                      \
        bfv0[ni] = *(const short8*)(pb_ + ni * 2048 + s0);                    \
        bfv1[ni] = *(const short8*)(pb_ + ni * 2048 + (s0 ^ 64));             \
      }                                                                       \
    }                                                                         \
    __VA_ARGS__;                                                              \
    if (DOWAIT) asm volatile("s_waitcnt vmcnt(4)" ::: "memory");              \
    __builtin_amdgcn_s_barrier();                                             \
    __builtin_amdgcn_s_setprio(1);                                            \
    _Pragma("unroll") for (int ni = 0; ni < 4; ++ni) {                        \
      acc[2 * (Q)][ni] = __builtin_amdgcn_mfma_f32_16x16x32_bf16(             \
          a00, bfv0[ni], acc[2 * (Q)][ni], 0, 0, 0);                          \
      acc[2 * (Q) + 1][ni] = __builtin_amdgcn_mfma_f32_16x16x32_bf16(         \
          a10, bfv0[ni], acc[2 * (Q) + 1][ni], 0, 0, 0);                      \
    }                                                                         \
    _Pragma("unroll") for (int ni = 0; ni < 4; ++ni) {                        \
      acc[2 * (Q)][ni] = __builtin_amdgcn_mfma_f32_16x16x32_bf16(             \
          a01, bfv1[ni], acc[2 * (Q)][ni], 0, 0, 0);                          \
      acc[2 * (Q) + 1][ni] = __builtin_amdgcn_mfma_f32_16x16x32_bf16(         \
          a11, bfv1[ni], acc[2 * (Q) + 1][ni], 0, 0, 0);                      \
    }                                                                         \
    __builtin_amdgcn_s_setprio(0);                                            \
    asm volatile("" ::: "memory");                                            \
  }

  // prologue: A(t0), B(t0), B(t1) = 12 loads; land tile0's 8, leave B(t1)=4
  STGA(0, 0, 0); STGA(0, 0, 1);
  STGB(0, 0, 0); STGB(0, 0, 1);
  STGB(1, 1, 0); STGB(1, 1, 1);
  asm volatile("s_waitcnt vmcnt(4)" ::: "memory");
  __builtin_amdgcn_s_barrier();
  asm volatile("" ::: "memory");

  for (int it = 0; it < NIT; ++it) {
    const int t1 = 2 * it + 1, t2 = 2 * it + 2, t3 = 2 * it + 3;
    short8 bfv0[4], bfv1[4];
    PH(0, 0, 1, 0, STGA(1, t1, 0); STGA(1, t1, 1));   // ph1
    PH(0, 1, 0, 0, STGB(0, t2, 0));                   // ph2
    PH(0, 2, 0, 0, STGB(0, t2, 1));                   // ph3
    PH(0, 3, 0, 1, );                                 // ph4: vmcnt(4)
    PH(1, 0, 1, 0, STGA(0, t2, 0));                   // ph5
    PH(1, 1, 0, 0, STGA(0, t2, 1));                   // ph6
    PH(1, 2, 0, 0, STGB(1, t3, 0));                   // ph7
    PH(1, 3, 0, 1, STGB(1, t3, 1));                   // ph8: vmcnt(4)
  }
  asm volatile("s_waitcnt vmcnt(0)" ::: "memory");    // drain tail stages

#undef STGA
#undef STGB
#undef PH

  // epilogue: C/D layout col=lane&15, row=(lane>>4)*4+j (m89-verified)
  const int row0 = bm * 256 + wr * 128 + ((lane >> 4) << 2);
  const int col0 = bn * 256 + wc * 64 + (lane & 15);
#pragma unroll
  for (int ni = 0; ni < 4; ++ni) {
    const int col = col0 + ni * 16;
    const float bv = HAS_BIAS ? bias[col] : 0.0f;
#pragma unroll
    for (int mi = 0; mi < 8; ++mi) {
#pragma unroll
      for (int j2 = 0; j2 < 4; ++j2) {
        const int row = row0 + mi * 16 + j2;
        float v = acc[mi][ni][j2] + bv;
        if (RELU) v = fmaxf(v, 0.0f);
        if (OUT_BF16)
          ((ushort*)Cout)[(size_t)row * N + col] = f2bf(v);
        else
          ((float*)Cout)[(size_t)row * N + col] = v;
      }
    }
  }
}

// ---------------- SAGE1 aggregation + combine (bf16 hlr1) -------------------
__global__ __launch_bounds__(256) void sage1_agg(
    const ushort* __restrict__ hlr1, const int* __restrict__ offs,
    const int* __restrict__ csr, const float* __restrict__ inv,
    const float* __restrict__ lb, ushort* __restrict__ h3) {
  const int dn = blockIdx.x;
  const int f4 = threadIdx.x * 4;
  float ax = 0.f, ay = 0.f, az = 0.f, aw = 0.f;
  const int e0 = offs[dn], e1 = offs[dn + 1];
  for (int e = e0; e < e1; ++e) {
    const int s = csr[e];
    const ushort4v v = *(const ushort4v*)(hlr1 + (size_t)s * 2048 + f4);
    ax += bf2f(v[0]); ay += bf2f(v[1]); az += bf2f(v[2]); aw += bf2f(v[3]);
  }
  const float iv = inv[dn];
  const ushort4v hr = *(const ushort4v*)(hlr1 + (size_t)dn * 2048 + 1024 + f4);
  const float4 bb = *(const float4*)(lb + f4);
  ushort4v o;
  o[0] = f2bf(fmaxf(ax * iv + bb.x + bf2f(hr[0]), 0.0f));
  o[1] = f2bf(fmaxf(ay * iv + bb.y + bf2f(hr[1]), 0.0f));
  o[2] = f2bf(fmaxf(az * iv + bb.z + bf2f(hr[2]), 0.0f));
  o[3] = f2bf(fmaxf(aw * iv + bb.w + bf2f(hr[3]), 0.0f));
  *(ushort4v*)(h3 + (size_t)dn * 1024 + f4) = o;
}

// ---------------- SAGE2 projections v2 (weights in LDS, 16 rows/block) ------
__global__ __launch_bounds__(256) void sage2_mm(
    const ushort* __restrict__ h3, const float* __restrict__ wl,
    const float* __restrict__ wr, float* __restrict__ hl2, float* __restrict__ hr2) {
  __shared__ float wds[20480];   // [0..10239]=wl, [10240..20479]=wr
  const int t = threadIdx.x;
  for (int i = t; i < 2560; i += 256)
    *(float4*)&wds[i * 4] = *(const float4*)&wl[i * 4];
  for (int i = t; i < 2560; i += 256)
    *(float4*)&wds[10240 + i * 4] = *(const float4*)&wr[i * 4];
  __syncthreads();

  const int r = t >> 4, c = t & 15;
  const int row = blockIdx.x * 16 + r;

  float hv[64];
#pragma unroll
  for (int ii = 0; ii < 8; ++ii) {
    ushort8v p = *(const ushort8v*)(h3 + (size_t)row * 1024 + c * 64 + ii * 8);
#pragma unroll
    for (int k = 0; k < 8; ++k) hv[ii * 8 + k] = bf2f(p[k]);
  }

  float al[10] = {}, ar[10] = {};
#pragma unroll
  for (int j = 0; j < 10; ++j) {
    const int base = j * 1024 + c * 64;
#pragma unroll
    for (int ii = 0; ii < 16; ++ii) {
      const int f = (ii + c) & 15;    // staggered float4 index
      const float4 lv = *(const float4*)&wds[base + f * 4];
      const float4 rv = *(const float4*)&wds[10240 + base + f * 4];
      const float h0 = hv[f * 4], h1 = hv[f * 4 + 1],
                  h2 = hv[f * 4 + 2], h3v = hv[f * 4 + 3];
      al[j] = fmaf(h0, lv.x, fmaf(h1, lv.y, fmaf(h2, lv.z, fmaf(h3v, lv.w, al[j]))));
      ar[j] = fmaf(h0, rv.x, fmaf(h1, rv.y, fmaf(h2, rv.z, fmaf(h3v, rv.w, ar[j]))));
    }
  }
#pragma unroll
  for (int j = 0; j < 10; ++j) {
#pragma unroll
    for (int off = 8; off > 0; off >>= 1) {
      al[j] += __shfl_down(al[j], off);
      ar[j] += __shfl_down(ar[j], off);
    }
  }
  if (c == 0) {
#pragma unroll
    for (int j = 0; j < 10; ++j) {
      hl2[(size_t)row * 10 + j] = al[j];
      hr2[(size_t)row * 10 + j] = ar[j];
    }
  }
}

// ---------------- SAGE2 aggregation + combine + softmax (4 nodes/block) -----
__global__ __launch_bounds__(256) void sage2_final(
    const float* __restrict__ hl2, const float* __restrict__ hr2,
    const int* __restrict__ offs, const int* __restrict__ csr,
    const float* __restrict__ inv, const float* __restrict__ lb,
    float* __restrict__ out) {
  const int dn = blockIdx.x * 4 + (threadIdx.x >> 6);
  const int l = threadIdx.x & 63;
  float a[10] = {};
  const int e0 = offs[dn], e1 = offs[dn + 1];
  for (int e = e0 + l; e < e1; e += 64) {
    const int s = csr[e];
#pragma unroll
    for (int j = 0; j < 10; ++j) a[j] += hl2[(size_t)s * 10 + j];
  }
#pragma unroll
  for (int j = 0; j < 10; ++j)
#pragma unroll
    for (int off = 32; off > 0; off >>= 1) a[j] += __shfl_down(a[j], off);
  if (l == 0) {
    const float iv = inv[dn];
    float v[10];
    float m = -1e30f;
#pragma unroll
    for (int j = 0; j < 10; ++j) {
      v[j] = fmaxf(a[j] * iv + lb[j] + hr2[(size_t)dn * 10 + j], 0.0f);
      m = fmaxf(m, v[j]);
    }
    float ssum = 0.0f;
#pragma unroll
    for (int j = 0; j < 10; ++j) { v[j] = __expf(v[j] - m); ssum += v[j]; }
    const float r = 1.0f / ssum;
#pragma unroll
    for (int j = 0; j < 10; ++j) out[(size_t)dn * 10 + j] = v[j] * r;
  }
}

// ---------------------------------------------------------------------------
extern "C" void kernel_launch(void* const* d_in, const int* in_sizes, int n_in,
                              void* d_out, int out_size, void* d_ws, size_t ws_size,
                              hipStream_t stream) {
  const float* x    = (const float*)d_in[0];
  const int*   ei   = (const int*)d_in[1];
  const float* w1   = (const float*)d_in[2];
  const float* b1   = (const float*)d_in[3];
  const float* w2   = (const float*)d_in[4];
  const float* b2   = (const float*)d_in[5];
  const float* s1lw = (const float*)d_in[6];
  const float* s1lb = (const float*)d_in[7];
  const float* s1rw = (const float*)d_in[8];
  const float* s2lw = (const float*)d_in[9];
  const float* s2lb = (const float*)d_in[10];
  const float* s2rw = (const float*)d_in[11];
  float* out = (float*)d_out;
  char* ws = (char*)d_ws;

  const int E = in_sizes[1] / 2;  // 262144
  const int Nn = 8192;

  // allow 128 KiB dynamic LDS for the GEMM instantiations (idempotent)
  hipFuncSetAttribute((const void*)&gemm256<1, 1, 1>,
                      hipFuncAttributeMaxDynamicSharedMemorySize, 131072);
  hipFuncSetAttribute((const void*)&gemm256<1, 0, 0>,
                      hipFuncAttributeMaxDynamicSharedMemorySize, 131072);

  // ---- workspace layout (bytes) ----
  ushort* xb  = (ushort*)(ws + 0L);           // 256 MiB
  ushort* w1b = (ushort*)(ws + 268435456L);   // 128 MiB
  ushort* h1  = (ushort*)(ws + 402653184L);   //  64 MiB
  ushort* w2b = (ushort*)(ws + 469762048L);   //  16 MiB
  ushort* h2  = (ushort*)(ws + 486539264L);   //  32 MiB
  ushort* ws1 = (ushort*)(ws + 520093696L);   //   8 MiB  [s1_l_w ; s1_r_w]
  char* csrb = ws + 528482304L;
  int*   deg  = (int*)(csrb);
  int*   fill = (int*)(csrb + 32768);
  int*   offs = (int*)(csrb + 65536);
  float* inv  = (float*)(csrb + 98816);
  int*   csr  = (int*)(csrb + 131584);
  // region reuse (xb dead after GEMM1, h1 dead after GEMM2):
  ushort* hlr1 = (ushort*)(ws + 0L);                // 32 MiB bf16 [hl1 | hr1]
  ushort* h3   = (ushort*)(ws + 67108864L);         // 16 MiB
  float*  hl2  = (float*)(ws + 83886080L);
  float*  hr2  = (float*)(ws + 84213760L);

  const int* esrc = ei;
  const int* edst = ei + E;

  hipMemsetAsync(deg, 0, 65536, stream);  // deg + fill counters

  // bf16 conversions (separate launches — R14 fusion regressed)
  cvt_f32_bf16<<<4096, 256, 0, stream>>>(x, xb, 16777216L);
  cvt_f32_bf16<<<2048, 256, 0, stream>>>(w1, w1b, 8388608L);
  cvt_f32_bf16<<<1024, 256, 0, stream>>>(w2, w2b, 1048576L);
  cvt_f32_bf16<<<256, 256, 0, stream>>>(s1lw, ws1, 262144L);
  cvt_f32_bf16<<<256, 256, 0, stream>>>(s1rw, ws1 + 2097152L, 262144L);

  // CSR build
  edge_count<<<(E + 255) / 256, 256, 0, stream>>>(edst, E, deg);
  scan_k<<<1, 256, 0, stream>>>(deg, offs, inv, Nn);
  edge_fill<<<(E + 255) / 256, 256, 0, stream>>>(esrc, edst, E, offs, fill, csr);

  // MLP (256x256-tile GEMMs, 128 KiB dynamic LDS, 8-phase pipeline)
  gemm256<1, 1, 1><<<512, 512, 131072, stream>>>(xb, w1b, b1, h1, 8192, 4096, 16384);
  gemm256<1, 1, 1><<<256, 512, 131072, stream>>>(h1, w2b, b2, h2, 8192, 2048, 4096);
  // fused SAGE1 projections: [hl1 | hr1] = h2 @ [s1_l_w ; s1_r_w]^T  (bf16 out)
  gemm256<1, 0, 0><<<256, 512, 131072, stream>>>(h2, ws1, nullptr, hlr1, 8192, 2048, 2048);

  sage1_agg<<<8192, 256, 0, stream>>>(hlr1, offs, csr, inv, s1lb, h3);
  sage2_mm<<<512, 256, 0, stream>>>(h3, s2lw, s2rw, hl2, hr2);
  sage2_final<<<2048, 256, 0, stream>>>(hl2, hr2, offs, csr, inv, s2lb, out);
}